// Round 2
// baseline (257.095 us; speedup 1.0000x reference)
//
#include <hip/hip_runtime.h>
#include <math.h>

// GCN collapsed to scalar-per-node form:
//   deg[c] = 1 + #{col==c};  dinv = rsqrt(deg);  u = dinv*x
//   s_raw[c] = sum_{col=c} u[row];  sc = dinv*s_raw + dinv^2*x
//   w_raw[r] = sum_{row=r} dinv[col];  w = dinv*(w_raw + dinv)
//   total[k] = sum_i w[i]*relu(sc[i]*W1[k]+b1[k]);  out = total/N @ W2 + b2
//
// R7 == R6 with the cnt-aliasing fix: R6 placed the epilogue ticket counter
// at ints+64 while the ints region was only 64 ints -> cnt aliased SC[0],
// scatter clobbered it, last-block epilogue never ran, out stayed 0.
// ints region is now 512 bytes (128 ints); cnt = ints+64 is inside it.
//
// R6 changes (kept): (a) hist_deg+finalize_deg fused into bucket-resident
// deg_finalize (25 blocks x 1024, whole-bucket LDS hist) -- removes the
// 19.6MB Pd partial round-trip and one launch. (b) final_out fused into
// fused_node via device-scope ticket. (c) scatter grid = exact tile count.

constexpr int BKT_BITS = 12;
constexpr int BKT_SIZE = 1 << BKT_BITS;   // 4096
constexpr int NBMAX    = 32;
constexpr int CAP      = 67584;           // per-bucket region capacity (mean+8sigma)
constexpr int SLICES   = 12;              // gather-hist slices per bucket
constexpr int EPT      = 8;               // edges per thread in scatter

__global__ void init_misc(int* __restrict__ curC, int* __restrict__ curR,
                          float* __restrict__ total, unsigned* __restrict__ cnt) {
    int t = threadIdx.x;
    if (t < NBMAX) { curC[t] = t * CAP; curR[t] = t * CAP; }
    if (t < 128) total[t] = 0.0f;
    if (t == 0) *cnt = 0u;
}

__global__ void scatter_edges(const int* __restrict__ row, const int* __restrict__ col,
                              int* __restrict__ SC, int* __restrict__ SR,
                              int* __restrict__ curC, int* __restrict__ curR, int E) {
    __shared__ int hC[NBMAX], hR[NBMAX], bC[NBMAX], bR[NBMAX];
    const int TILE = blockDim.x * EPT;
    const int nTiles = (E + TILE - 1) / TILE;
    for (int t = blockIdx.x; t < nTiles; t += gridDim.x) {
        const int myBase = t * TILE + threadIdx.x * EPT;
        int r[EPT], c[EPT];
        if (myBase + EPT <= E) {
            int4 r0 = *reinterpret_cast<const int4*>(row + myBase);
            int4 r1 = *reinterpret_cast<const int4*>(row + myBase + 4);
            int4 c0 = *reinterpret_cast<const int4*>(col + myBase);
            int4 c1 = *reinterpret_cast<const int4*>(col + myBase + 4);
            r[0]=r0.x; r[1]=r0.y; r[2]=r0.z; r[3]=r0.w;
            r[4]=r1.x; r[5]=r1.y; r[6]=r1.z; r[7]=r1.w;
            c[0]=c0.x; c[1]=c0.y; c[2]=c0.z; c[3]=c0.w;
            c[4]=c1.x; c[5]=c1.y; c[6]=c1.z; c[7]=c1.w;
        } else {
#pragma unroll
            for (int j = 0; j < EPT; ++j) {
                int e = myBase + j;
                r[j] = (e < E) ? row[e] : -1;
                c[j] = (e < E) ? col[e] : -1;
            }
        }
        if (threadIdx.x < NBMAX) { hC[threadIdx.x] = 0; hR[threadIdx.x] = 0; }
        __syncthreads();
#pragma unroll
        for (int j = 0; j < EPT; ++j) {
            if (r[j] >= 0) {
                atomicAdd(&hC[c[j] >> BKT_BITS], 1);
                atomicAdd(&hR[r[j] >> BKT_BITS], 1);
            }
        }
        __syncthreads();
        if (threadIdx.x < NBMAX) {
            bC[threadIdx.x] = atomicAdd(&curC[threadIdx.x], hC[threadIdx.x]);
            hC[threadIdx.x] = 0;
            bR[threadIdx.x] = atomicAdd(&curR[threadIdx.x], hR[threadIdx.x]);
            hR[threadIdx.x] = 0;
        }
        __syncthreads();
#pragma unroll
        for (int j = 0; j < EPT; ++j) {
            if (r[j] >= 0) {
                int kb = c[j] >> BKT_BITS;
                int idx = bC[kb] + atomicAdd(&hC[kb], 1);
                if (idx < (kb + 1) * CAP)           // overflow clamp (8-sigma margin)
                    SC[idx] = ((c[j] & (BKT_SIZE - 1)) << 17) | r[j];
                int kb2 = r[j] >> BKT_BITS;
                int idx2 = bR[kb2] + atomicAdd(&hR[kb2], 1);
                if (idx2 < (kb2 + 1) * CAP)
                    SR[idx2] = ((r[j] & (BKT_SIZE - 1)) << 17) | c[j];
            }
        }
        __syncthreads();
    }
}

// One block per bucket: whole-bucket deg hist in LDS, then dinv/u written
// directly. Replaces hist_deg (9.8MB partial write) + finalize_deg (9.8MB
// partial read). Bucket edge stream is L2-hot (just written by scatter).
__global__ __launch_bounds__(1024)
void deg_finalize(const int* __restrict__ SC, const int* __restrict__ curC,
                  const float* __restrict__ x, float* __restrict__ dinv,
                  float* __restrict__ u, int N) {
    __shared__ float bins[BKT_SIZE];
    const int b = blockIdx.x;
    const int base = b * CAP;
    int len = curC[b] - base;
    len = len < CAP ? len : CAP;
    for (int i = threadIdx.x; i < BKT_SIZE; i += 1024) bins[i] = 0.0f;
    __syncthreads();
    for (int e = base + threadIdx.x; e < base + len; e += 1024)
        atomicAdd(&bins[SC[e] >> 17], 1.0f);
    __syncthreads();
    const int nb = b << BKT_BITS;
    for (int i = threadIdx.x; i < BKT_SIZE; i += 1024) {
        int node = nb + i;
        if (node < N) {
            float di = rsqrtf(1.0f + bins[i]);   // +1 = self loop
            dinv[node] = di;
            u[node] = di * x[node];
        }
    }
}

// first half of grid: s-hist over SC gathering u; second half: w-hist over SR
// gathering dinv. Branch is block-uniform.
__global__ void hist_gather_both(const int* __restrict__ SC, const int* __restrict__ SR,
                                 const int* __restrict__ curC, const int* __restrict__ curR,
                                 const float* __restrict__ u, const float* __restrict__ dinv,
                                 float* __restrict__ Ps, float* __restrict__ Pw,
                                 int stride, int half) {
    __shared__ float bins[BKT_SIZE];
    const bool isW = blockIdx.x >= half;
    const int id = isW ? blockIdx.x - half : blockIdx.x;
    const int* S = isW ? SR : SC;
    const int* cur = isW ? curR : curC;
    const float* val = isW ? dinv : u;
    float* P = isW ? Pw : Ps;
    const int b = id / SLICES, s = id % SLICES;
    const int base = b * CAP;
    int len = cur[b] - base;
    len = len < CAP ? len : CAP;
    const int lo = base + (int)((long long)len * s / SLICES);
    const int hi = base + (int)((long long)len * (s + 1) / SLICES);
    for (int i = threadIdx.x; i < BKT_SIZE; i += blockDim.x) bins[i] = 0.0f;
    __syncthreads();
    for (int e = lo + threadIdx.x; e < hi; e += blockDim.x) {
        int v = S[e];
        atomicAdd(&bins[v >> 17], val[v & 0x1FFFF]);
    }
    __syncthreads();
    float* dst = P + (size_t)s * stride + b * BKT_SIZE;
    for (int i = threadIdx.x; i < BKT_SIZE; i += blockDim.x) dst[i] = bins[i];
}

// Fused: finalize sc/w for 256 nodes, per-block k-phase from LDS broadcasts,
// atomic-accumulate into total[128]; LAST block (device-scope ticket) runs
// the 128x400 W2 epilogue inline (replaces the final_out launch).
__global__ void fused_node(const float* __restrict__ Ps, const float* __restrict__ Pw,
                           const float* __restrict__ dinv, const float* __restrict__ x,
                           const float* __restrict__ W1, const float* __restrict__ b1,
                           float* __restrict__ total, int N, int stride,
                           const float* __restrict__ W2, const float* __restrict__ b2,
                           float* __restrict__ out, int OUT, float invN,
                           unsigned* __restrict__ cnt) {
    __shared__ float scs[256];
    __shared__ float ws[256];
    __shared__ float red[256];
    __shared__ unsigned lastFlag;
    const int tid = threadIdx.x;
    const int i = blockIdx.x * 256 + tid;
    float scv = 0.0f, wv = 0.0f;
    if (i < N) {
        float sr = 0.0f, wr = 0.0f;
        for (int s = 0; s < SLICES; ++s) {
            sr += Ps[(size_t)s * stride + i];
            wr += Pw[(size_t)s * stride + i];
        }
        float di = dinv[i];
        scv = di * sr + di * di * x[i];
        wv  = di * (wr + di);
    }
    scs[tid] = scv;
    ws[tid]  = wv;     // 0 for i>=N -> zero contribution
    __syncthreads();
    const int k = tid & 127;
    const int base = (tid >> 7) * 128;
    const float w1k = W1[k];
    const float b1k = b1[k];
    float acc = 0.0f;
#pragma unroll 4
    for (int j = 0; j < 128; ++j) {
        float h = scs[base + j] * w1k + b1k;
        h = h > 0.0f ? h : 0.0f;
        acc += ws[base + j] * h;
    }
    red[tid] = acc;
    __syncthreads();
    if (tid < 128)
        atomicAdd(&total[k], red[tid] + red[tid + 128]);
    // ---- last-block epilogue (out = total/N @ W2 + b2) ----
    __threadfence();                       // order total-atomics before ticket
    __syncthreads();
    if (tid == 0)
        lastFlag = (atomicAdd(cnt, 1u) == (unsigned)(gridDim.x - 1)) ? 1u : 0u;
    __syncthreads();
    if (lastFlag) {
        __shared__ float tv[128];
        if (tid < 128)
            tv[tid] = atomicAdd(&total[tid], 0.0f) * invN;  // coherent device-scope read
        __syncthreads();
        for (int d = tid; d < OUT; d += 256) {
            float a = b2[d];
#pragma unroll 4
            for (int kk = 0; kk < 128; ++kk) a += tv[kk] * W2[kk * OUT + d];
            out[d] = a;
        }
    }
}

extern "C" void kernel_launch(void* const* d_in, const int* in_sizes, int n_in,
                              void* d_out, int out_size, void* d_ws, size_t ws_size,
                              hipStream_t stream) {
    const float* x          = (const float*)d_in[0];
    const int*   edge_index = (const int*)  d_in[1];
    const float* W1         = (const float*)d_in[2];
    const float* b1         = (const float*)d_in[3];
    const float* W2         = (const float*)d_in[4];
    const float* b2         = (const float*)d_in[5];
    float* out = (float*)d_out;

    const int N   = in_sizes[0];      // 100000
    const int E   = in_sizes[1] / 2;  // 1600000
    const int OUT = in_sizes[5];      // 400

    const int* row = edge_index;
    const int* col = edge_index + E;

    const int NB = (N + BKT_SIZE - 1) >> BKT_BITS;   // 25
    const int stride = NB * BKT_SIZE;                // 102400

    // workspace layout
    char* p = (char*)d_ws;
    float* dinv  = (float*)p; p += (size_t)N * 4;
    float* u     = (float*)p; p += (size_t)N * 4;
    float* total = (float*)p; p += 512;
    int*   ints  = (int*)p;   p += 512;              // 128 ints: curC|curR|cnt
    int*   SC    = (int*)p;   p += (size_t)NB * CAP * 4;
    int*   SR    = (int*)p;   p += (size_t)NB * CAP * 4;
    float* P     = (float*)p;                        // 2*SLICES*stride floats
    float* Ps    = P;
    float* Pw    = P + (size_t)SLICES * stride;

    int* curC = ints;
    int* curR = ints + 32;
    unsigned* cnt = (unsigned*)(ints + 64);          // inside the 128-int region now

    const int TILE   = 256 * EPT;
    const int nTiles = (E + TILE - 1) / TILE;        // 782 -> one tile per block

    init_misc<<<1, 128, 0, stream>>>(curC, curR, total, cnt);
    scatter_edges<<<nTiles, 256, 0, stream>>>(row, col, SC, SR, curC, curR, E);
    deg_finalize<<<NB, 1024, 0, stream>>>(SC, curC, x, dinv, u, N);
    const int half = NB * SLICES;
    hist_gather_both<<<2 * half, 256, 0, stream>>>(SC, SR, curC, curR, u, dinv,
                                                   Ps, Pw, stride, half);
    fused_node<<<(N + 255) / 256, 256, 0, stream>>>(Ps, Pw, dinv, x, W1, b1,
                                                    total, N, stride,
                                                    W2, b2, out, OUT,
                                                    1.0f / (float)N, cnt);
}

// Round 3
// 192.010 us; speedup vs baseline: 1.3390x; 1.3390x over previous
//
#include <hip/hip_runtime.h>
#include <math.h>

// GCN collapsed to scalar-per-node form:
//   deg[c] = 1 + #{col==c};  dinv = rsqrt(deg);  u = dinv*x
//   s_raw[c] = sum_{col=c} u[row];  sc = dinv*s_raw + dinv^2*x
//   w_raw[r] = sum_{row=r} dinv[col];  w = dinv*(w_raw + dinv)
//   total[k] = sum_i w[i]*relu(sc[i]*W1[k]+b1[k]);  out = total/N @ W2 + b2
//
// R8: (a) REVERT deg to sliced hist_deg(600 blocks)+finalize_deg -- R7's
// 25-block deg_finalize was LDS-atomic-throughput-bound: 1.6M ds_add_f32
// on 25 CUs @ ~3cy/lane = 87us measured. Histogram cost = LDS-atomic
// lane-ops / CUs-covered; slicing wins 8x over the 19.6MB traffic saving.
// (b) scatter: single rtn-atomic per edge-side replaces count+place pair
// (6.4M -> 3.2M LDS atomic lane-ops, model predicts -12us). (c) keep R7
// exact-fit scatter grid + last-block W2 epilogue (cnt inside ints[128]).

constexpr int BKT_BITS = 12;
constexpr int BKT_SIZE = 1 << BKT_BITS;   // 4096
constexpr int NBMAX    = 32;
constexpr int CAP      = 67584;           // per-bucket region capacity (mean+8sigma)
constexpr int SLICES   = 12;              // gather-hist slices per bucket
constexpr int SLICES_D = 24;              // deg-hist slices per bucket
constexpr int EPT      = 8;               // edges per thread in scatter

__global__ void init_misc(int* __restrict__ curC, int* __restrict__ curR,
                          float* __restrict__ total, unsigned* __restrict__ cnt) {
    int t = threadIdx.x;
    if (t < NBMAX) { curC[t] = t * CAP; curR[t] = t * CAP; }
    if (t < 128) total[t] = 0.0f;
    if (t == 0) *cnt = 0u;
}

// One tile (2048 edges) per block. Single return-atomic per edge-side gives
// the within-tile slot; global range reserved once per bucket after sync.
__global__ void scatter_edges(const int* __restrict__ row, const int* __restrict__ col,
                              int* __restrict__ SC, int* __restrict__ SR,
                              int* __restrict__ curC, int* __restrict__ curR, int E) {
    __shared__ int hC[NBMAX], hR[NBMAX], bC[NBMAX], bR[NBMAX];
    const int TILE = blockDim.x * EPT;
    const int myBase = blockIdx.x * TILE + threadIdx.x * EPT;
    int r[EPT], c[EPT];
    if (myBase + EPT <= E) {
        int4 r0 = *reinterpret_cast<const int4*>(row + myBase);
        int4 r1 = *reinterpret_cast<const int4*>(row + myBase + 4);
        int4 c0 = *reinterpret_cast<const int4*>(col + myBase);
        int4 c1 = *reinterpret_cast<const int4*>(col + myBase + 4);
        r[0]=r0.x; r[1]=r0.y; r[2]=r0.z; r[3]=r0.w;
        r[4]=r1.x; r[5]=r1.y; r[6]=r1.z; r[7]=r1.w;
        c[0]=c0.x; c[1]=c0.y; c[2]=c0.z; c[3]=c0.w;
        c[4]=c1.x; c[5]=c1.y; c[6]=c1.z; c[7]=c1.w;
    } else {
#pragma unroll
        for (int j = 0; j < EPT; ++j) {
            int e = myBase + j;
            r[j] = (e < E) ? row[e] : -1;
            c[j] = (e < E) ? col[e] : -1;
        }
    }
    if (threadIdx.x < NBMAX) { hC[threadIdx.x] = 0; hR[threadIdx.x] = 0; }
    __syncthreads();
    int offC[EPT], offR[EPT];
#pragma unroll
    for (int j = 0; j < EPT; ++j) {
        if (r[j] >= 0) {
            offC[j] = atomicAdd(&hC[c[j] >> BKT_BITS], 1);   // rtn-atomic: slot
            offR[j] = atomicAdd(&hR[r[j] >> BKT_BITS], 1);
        }
    }
    __syncthreads();
    if (threadIdx.x < NBMAX) {
        bC[threadIdx.x] = atomicAdd(&curC[threadIdx.x], hC[threadIdx.x]);
        bR[threadIdx.x] = atomicAdd(&curR[threadIdx.x], hR[threadIdx.x]);
    }
    __syncthreads();
#pragma unroll
    for (int j = 0; j < EPT; ++j) {
        if (r[j] >= 0) {
            int kb = c[j] >> BKT_BITS;
            int idx = bC[kb] + offC[j];
            if (idx < (kb + 1) * CAP)           // overflow clamp (8-sigma margin)
                SC[idx] = ((c[j] & (BKT_SIZE - 1)) << 17) | r[j];
            int kb2 = r[j] >> BKT_BITS;
            int idx2 = bR[kb2] + offR[j];
            if (idx2 < (kb2 + 1) * CAP)
                SR[idx2] = ((r[j] & (BKT_SIZE - 1)) << 17) | c[j];
        }
    }
}

__global__ void hist_deg(const int* __restrict__ SC, const int* __restrict__ cur,
                         float* __restrict__ P, int stride) {
    __shared__ float bins[BKT_SIZE];
    const int b = blockIdx.x / SLICES_D, s = blockIdx.x % SLICES_D;
    const int base = b * CAP;
    int len = cur[b] - base;
    len = len < CAP ? len : CAP;
    const int lo = base + (int)((long long)len * s / SLICES_D);
    const int hi = base + (int)((long long)len * (s + 1) / SLICES_D);
    for (int i = threadIdx.x; i < BKT_SIZE; i += blockDim.x) bins[i] = 0.0f;
    __syncthreads();
    for (int e = lo + threadIdx.x; e < hi; e += blockDim.x)
        atomicAdd(&bins[SC[e] >> 17], 1.0f);
    __syncthreads();
    float* dst = P + (size_t)s * stride + b * BKT_SIZE;
    for (int i = threadIdx.x; i < BKT_SIZE; i += blockDim.x) dst[i] = bins[i];
}

__global__ void finalize_deg(const float* __restrict__ Pd, const float* __restrict__ x,
                             float* __restrict__ dinv, float* __restrict__ u,
                             int N, int stride) {
    int i = blockIdx.x * blockDim.x + threadIdx.x;
    if (i >= N) return;
    float d = 1.0f;  // self loop
    for (int s = 0; s < SLICES_D; ++s) d += Pd[(size_t)s * stride + i];
    float di = rsqrtf(d);
    dinv[i] = di;
    u[i] = di * x[i];
}

// first half of grid: s-hist over SC gathering u; second half: w-hist over SR
// gathering dinv. Branch is block-uniform.
__global__ void hist_gather_both(const int* __restrict__ SC, const int* __restrict__ SR,
                                 const int* __restrict__ curC, const int* __restrict__ curR,
                                 const float* __restrict__ u, const float* __restrict__ dinv,
                                 float* __restrict__ Ps, float* __restrict__ Pw,
                                 int stride, int half) {
    __shared__ float bins[BKT_SIZE];
    const bool isW = blockIdx.x >= half;
    const int id = isW ? blockIdx.x - half : blockIdx.x;
    const int* S = isW ? SR : SC;
    const int* cur = isW ? curR : curC;
    const float* val = isW ? dinv : u;
    float* P = isW ? Pw : Ps;
    const int b = id / SLICES, s = id % SLICES;
    const int base = b * CAP;
    int len = cur[b] - base;
    len = len < CAP ? len : CAP;
    const int lo = base + (int)((long long)len * s / SLICES);
    const int hi = base + (int)((long long)len * (s + 1) / SLICES);
    for (int i = threadIdx.x; i < BKT_SIZE; i += blockDim.x) bins[i] = 0.0f;
    __syncthreads();
    for (int e = lo + threadIdx.x; e < hi; e += blockDim.x) {
        int v = S[e];
        atomicAdd(&bins[v >> 17], val[v & 0x1FFFF]);
    }
    __syncthreads();
    float* dst = P + (size_t)s * stride + b * BKT_SIZE;
    for (int i = threadIdx.x; i < BKT_SIZE; i += blockDim.x) dst[i] = bins[i];
}

// Fused: finalize sc/w for 256 nodes, per-block k-phase from LDS broadcasts,
// atomic-accumulate into total[128]; LAST block (device-scope ticket) runs
// the 128x400 W2 epilogue inline.
__global__ void fused_node(const float* __restrict__ Ps, const float* __restrict__ Pw,
                           const float* __restrict__ dinv, const float* __restrict__ x,
                           const float* __restrict__ W1, const float* __restrict__ b1,
                           float* __restrict__ total, int N, int stride,
                           const float* __restrict__ W2, const float* __restrict__ b2,
                           float* __restrict__ out, int OUT, float invN,
                           unsigned* __restrict__ cnt) {
    __shared__ float scs[256];
    __shared__ float ws[256];
    __shared__ float red[256];
    __shared__ unsigned lastFlag;
    const int tid = threadIdx.x;
    const int i = blockIdx.x * 256 + tid;
    float scv = 0.0f, wv = 0.0f;
    if (i < N) {
        float sr = 0.0f, wr = 0.0f;
        for (int s = 0; s < SLICES; ++s) {
            sr += Ps[(size_t)s * stride + i];
            wr += Pw[(size_t)s * stride + i];
        }
        float di = dinv[i];
        scv = di * sr + di * di * x[i];
        wv  = di * (wr + di);
    }
    scs[tid] = scv;
    ws[tid]  = wv;     // 0 for i>=N -> zero contribution
    __syncthreads();
    const int k = tid & 127;
    const int base = (tid >> 7) * 128;
    const float w1k = W1[k];
    const float b1k = b1[k];
    float acc = 0.0f;
#pragma unroll 4
    for (int j = 0; j < 128; ++j) {
        float h = scs[base + j] * w1k + b1k;
        h = h > 0.0f ? h : 0.0f;
        acc += ws[base + j] * h;
    }
    red[tid] = acc;
    __syncthreads();
    if (tid < 128)
        atomicAdd(&total[k], red[tid] + red[tid + 128]);
    // ---- last-block epilogue (out = total/N @ W2 + b2) ----
    __threadfence();                       // order total-atomics before ticket
    __syncthreads();
    if (tid == 0)
        lastFlag = (atomicAdd(cnt, 1u) == (unsigned)(gridDim.x - 1)) ? 1u : 0u;
    __syncthreads();
    if (lastFlag) {
        __shared__ float tv[128];
        if (tid < 128)
            tv[tid] = atomicAdd(&total[tid], 0.0f) * invN;  // coherent device-scope read
        __syncthreads();
        for (int d = tid; d < OUT; d += 256) {
            float a = b2[d];
#pragma unroll 4
            for (int kk = 0; kk < 128; ++kk) a += tv[kk] * W2[kk * OUT + d];
            out[d] = a;
        }
    }
}

extern "C" void kernel_launch(void* const* d_in, const int* in_sizes, int n_in,
                              void* d_out, int out_size, void* d_ws, size_t ws_size,
                              hipStream_t stream) {
    const float* x          = (const float*)d_in[0];
    const int*   edge_index = (const int*)  d_in[1];
    const float* W1         = (const float*)d_in[2];
    const float* b1         = (const float*)d_in[3];
    const float* W2         = (const float*)d_in[4];
    const float* b2         = (const float*)d_in[5];
    float* out = (float*)d_out;

    const int N   = in_sizes[0];      // 100000
    const int E   = in_sizes[1] / 2;  // 1600000
    const int OUT = in_sizes[5];      // 400

    const int* row = edge_index;
    const int* col = edge_index + E;

    const int NB = (N + BKT_SIZE - 1) >> BKT_BITS;   // 25
    const int stride = NB * BKT_SIZE;                // 102400

    // workspace layout
    char* p = (char*)d_ws;
    float* dinv  = (float*)p; p += (size_t)N * 4;
    float* u     = (float*)p; p += (size_t)N * 4;
    float* total = (float*)p; p += 512;
    int*   ints  = (int*)p;   p += 512;              // 128 ints: curC|curR|cnt
    int*   SC    = (int*)p;   p += (size_t)NB * CAP * 4;
    int*   SR    = (int*)p;   p += (size_t)NB * CAP * 4;
    float* P     = (float*)p;                        // max(SLICES_D, 2*SLICES)*stride
    float* Ps    = P;                                // aliases Pd (sequential phases)
    float* Pw    = P + (size_t)SLICES * stride;

    int* curC = ints;
    int* curR = ints + 32;
    unsigned* cnt = (unsigned*)(ints + 64);

    const int TILE   = 256 * EPT;
    const int nTiles = (E + TILE - 1) / TILE;        // 782 -> one tile per block

    init_misc<<<1, 128, 0, stream>>>(curC, curR, total, cnt);
    scatter_edges<<<nTiles, 256, 0, stream>>>(row, col, SC, SR, curC, curR, E);
    hist_deg<<<NB * SLICES_D, 256, 0, stream>>>(SC, curC, P, stride);
    finalize_deg<<<(N + 255) / 256, 256, 0, stream>>>(P, x, dinv, u, N, stride);
    const int half = NB * SLICES;
    hist_gather_both<<<2 * half, 256, 0, stream>>>(SC, SR, curC, curR, u, dinv,
                                                   Ps, Pw, stride, half);
    fused_node<<<(N + 255) / 256, 256, 0, stream>>>(Ps, Pw, dinv, x, W1, b1,
                                                    total, N, stride,
                                                    W2, b2, out, OUT,
                                                    1.0f / (float)N, cnt);
}

// Round 4
// 176.367 us; speedup vs baseline: 1.4577x; 1.0887x over previous
//
#include <hip/hip_runtime.h>
#include <math.h>

// GCN collapsed to scalar-per-node form:
//   deg[c] = 1 + #{col==c};  dinv = rsqrt(deg);  u = dinv*x
//   s_raw[c] = sum_{col=c} u[row];  sc = dinv*s_raw + dinv^2*x
//   w_raw[r] = sum_{row=r} dinv[col];  w = dinv*(w_raw + dinv)
//   total[k] = sum_i w[i]*relu(sc[i]*W1[k]+b1[k]);  out = total/N @ W2 + b2
//
// R9: fused_node was 55-60us with ALL pipes idle (VALUBusy 1.9%, occ 7%,
// BW 1%) -- stall, not work. Two fixes: (a) drop __threadfence() (lowers to
// buffer_wbl2 L2-writeback walk per block on gfx950; ordering is already
// guaranteed because total/cnt/reads are ALL device-scope atomics at the
// coherence point and __syncthreads drains vmcnt between them). (b) spread
// the total-accumulator atomics across 32 slot-groups tslot[32][128]
// (blockIdx&31) -- R8 concentrated 50K lane-RMWs into 2 cache lines.
// Epilogue sums 32x128 via atomic reads.
// Kept from R8: sliced hist_deg/finalize_deg, rtn-atomic scatter,
// exact-fit scatter grid, last-block W2 epilogue.

constexpr int BKT_BITS = 12;
constexpr int BKT_SIZE = 1 << BKT_BITS;   // 4096
constexpr int NBMAX    = 32;
constexpr int CAP      = 67584;           // per-bucket region capacity (mean+8sigma)
constexpr int SLICES   = 12;              // gather-hist slices per bucket
constexpr int SLICES_D = 24;              // deg-hist slices per bucket
constexpr int EPT      = 8;               // edges per thread in scatter
constexpr int NSLOT    = 32;              // accumulator slot-groups

__global__ void init_misc(int* __restrict__ curC, int* __restrict__ curR,
                          float* __restrict__ tslot, unsigned* __restrict__ cnt) {
    int t = threadIdx.x;
    if (t < NBMAX) { curC[t] = t * CAP; curR[t] = t * CAP; }
    for (int j = t; j < NSLOT * 128; j += 128) tslot[j] = 0.0f;
    if (t == 0) *cnt = 0u;
}

// One tile (2048 edges) per block. Single return-atomic per edge-side gives
// the within-tile slot; global range reserved once per bucket after sync.
__global__ void scatter_edges(const int* __restrict__ row, const int* __restrict__ col,
                              int* __restrict__ SC, int* __restrict__ SR,
                              int* __restrict__ curC, int* __restrict__ curR, int E) {
    __shared__ int hC[NBMAX], hR[NBMAX], bC[NBMAX], bR[NBMAX];
    const int TILE = blockDim.x * EPT;
    const int myBase = blockIdx.x * TILE + threadIdx.x * EPT;
    int r[EPT], c[EPT];
    if (myBase + EPT <= E) {
        int4 r0 = *reinterpret_cast<const int4*>(row + myBase);
        int4 r1 = *reinterpret_cast<const int4*>(row + myBase + 4);
        int4 c0 = *reinterpret_cast<const int4*>(col + myBase);
        int4 c1 = *reinterpret_cast<const int4*>(col + myBase + 4);
        r[0]=r0.x; r[1]=r0.y; r[2]=r0.z; r[3]=r0.w;
        r[4]=r1.x; r[5]=r1.y; r[6]=r1.z; r[7]=r1.w;
        c[0]=c0.x; c[1]=c0.y; c[2]=c0.z; c[3]=c0.w;
        c[4]=c1.x; c[5]=c1.y; c[6]=c1.z; c[7]=c1.w;
    } else {
#pragma unroll
        for (int j = 0; j < EPT; ++j) {
            int e = myBase + j;
            r[j] = (e < E) ? row[e] : -1;
            c[j] = (e < E) ? col[e] : -1;
        }
    }
    if (threadIdx.x < NBMAX) { hC[threadIdx.x] = 0; hR[threadIdx.x] = 0; }
    __syncthreads();
    int offC[EPT], offR[EPT];
#pragma unroll
    for (int j = 0; j < EPT; ++j) {
        if (r[j] >= 0) {
            offC[j] = atomicAdd(&hC[c[j] >> BKT_BITS], 1);   // rtn-atomic: slot
            offR[j] = atomicAdd(&hR[r[j] >> BKT_BITS], 1);
        }
    }
    __syncthreads();
    if (threadIdx.x < NBMAX) {
        bC[threadIdx.x] = atomicAdd(&curC[threadIdx.x], hC[threadIdx.x]);
        bR[threadIdx.x] = atomicAdd(&curR[threadIdx.x], hR[threadIdx.x]);
    }
    __syncthreads();
#pragma unroll
    for (int j = 0; j < EPT; ++j) {
        if (r[j] >= 0) {
            int kb = c[j] >> BKT_BITS;
            int idx = bC[kb] + offC[j];
            if (idx < (kb + 1) * CAP)           // overflow clamp (8-sigma margin)
                SC[idx] = ((c[j] & (BKT_SIZE - 1)) << 17) | r[j];
            int kb2 = r[j] >> BKT_BITS;
            int idx2 = bR[kb2] + offR[j];
            if (idx2 < (kb2 + 1) * CAP)
                SR[idx2] = ((r[j] & (BKT_SIZE - 1)) << 17) | c[j];
        }
    }
}

__global__ void hist_deg(const int* __restrict__ SC, const int* __restrict__ cur,
                         float* __restrict__ P, int stride) {
    __shared__ float bins[BKT_SIZE];
    const int b = blockIdx.x / SLICES_D, s = blockIdx.x % SLICES_D;
    const int base = b * CAP;
    int len = cur[b] - base;
    len = len < CAP ? len : CAP;
    const int lo = base + (int)((long long)len * s / SLICES_D);
    const int hi = base + (int)((long long)len * (s + 1) / SLICES_D);
    for (int i = threadIdx.x; i < BKT_SIZE; i += blockDim.x) bins[i] = 0.0f;
    __syncthreads();
    for (int e = lo + threadIdx.x; e < hi; e += blockDim.x)
        atomicAdd(&bins[SC[e] >> 17], 1.0f);
    __syncthreads();
    float* dst = P + (size_t)s * stride + b * BKT_SIZE;
    for (int i = threadIdx.x; i < BKT_SIZE; i += blockDim.x) dst[i] = bins[i];
}

__global__ void finalize_deg(const float* __restrict__ Pd, const float* __restrict__ x,
                             float* __restrict__ dinv, float* __restrict__ u,
                             int N, int stride) {
    int i = blockIdx.x * blockDim.x + threadIdx.x;
    if (i >= N) return;
    float d = 1.0f;  // self loop
    for (int s = 0; s < SLICES_D; ++s) d += Pd[(size_t)s * stride + i];
    float di = rsqrtf(d);
    dinv[i] = di;
    u[i] = di * x[i];
}

// first half of grid: s-hist over SC gathering u; second half: w-hist over SR
// gathering dinv. Branch is block-uniform.
__global__ void hist_gather_both(const int* __restrict__ SC, const int* __restrict__ SR,
                                 const int* __restrict__ curC, const int* __restrict__ curR,
                                 const float* __restrict__ u, const float* __restrict__ dinv,
                                 float* __restrict__ Ps, float* __restrict__ Pw,
                                 int stride, int half) {
    __shared__ float bins[BKT_SIZE];
    const bool isW = blockIdx.x >= half;
    const int id = isW ? blockIdx.x - half : blockIdx.x;
    const int* S = isW ? SR : SC;
    const int* cur = isW ? curR : curC;
    const float* val = isW ? dinv : u;
    float* P = isW ? Pw : Ps;
    const int b = id / SLICES, s = id % SLICES;
    const int base = b * CAP;
    int len = cur[b] - base;
    len = len < CAP ? len : CAP;
    const int lo = base + (int)((long long)len * s / SLICES);
    const int hi = base + (int)((long long)len * (s + 1) / SLICES);
    for (int i = threadIdx.x; i < BKT_SIZE; i += blockDim.x) bins[i] = 0.0f;
    __syncthreads();
    for (int e = lo + threadIdx.x; e < hi; e += blockDim.x) {
        int v = S[e];
        atomicAdd(&bins[v >> 17], val[v & 0x1FFFF]);
    }
    __syncthreads();
    float* dst = P + (size_t)s * stride + b * BKT_SIZE;
    for (int i = threadIdx.x; i < BKT_SIZE; i += blockDim.x) dst[i] = bins[i];
}

// Fused: finalize sc/w for 256 nodes, per-block k-phase from LDS broadcasts,
// atomic-accumulate into tslot[blockIdx&31][128]; LAST block (device-scope
// ticket) sums the 32x128 slots and runs the 128x400 W2 epilogue inline.
__global__ void fused_node(const float* __restrict__ Ps, const float* __restrict__ Pw,
                           const float* __restrict__ dinv, const float* __restrict__ x,
                           const float* __restrict__ W1, const float* __restrict__ b1,
                           float* __restrict__ tslot, int N, int stride,
                           const float* __restrict__ W2, const float* __restrict__ b2,
                           float* __restrict__ out, int OUT, float invN,
                           unsigned* __restrict__ cnt) {
    __shared__ float scs[256];
    __shared__ float ws[256];
    __shared__ float red[256];
    __shared__ unsigned lastFlag;
    const int tid = threadIdx.x;
    const int i = blockIdx.x * 256 + tid;
    float scv = 0.0f, wv = 0.0f;
    if (i < N) {
        float sr = 0.0f, wr = 0.0f;
        for (int s = 0; s < SLICES; ++s) {
            sr += Ps[(size_t)s * stride + i];
            wr += Pw[(size_t)s * stride + i];
        }
        float di = dinv[i];
        scv = di * sr + di * di * x[i];
        wv  = di * (wr + di);
    }
    scs[tid] = scv;
    ws[tid]  = wv;     // 0 for i>=N -> zero contribution
    __syncthreads();
    const int k = tid & 127;
    const int base = (tid >> 7) * 128;
    const float w1k = W1[k];
    const float b1k = b1[k];
    float acc = 0.0f;
#pragma unroll 4
    for (int j = 0; j < 128; ++j) {
        float h = scs[base + j] * w1k + b1k;
        h = h > 0.0f ? h : 0.0f;
        acc += ws[base + j] * h;
    }
    red[tid] = acc;
    __syncthreads();
    if (tid < 128)
        atomicAdd(&tslot[(blockIdx.x & (NSLOT - 1)) * 128 + k],
                  red[tid] + red[tid + 128]);
    // __syncthreads below drains vmcnt -> this block's tslot atomics are
    // acked at the coherence point before its ticket increments. No fence:
    // all cross-block traffic here is device-scope atomics.
    __syncthreads();
    if (tid == 0)
        lastFlag = (atomicAdd(cnt, 1u) == (unsigned)(gridDim.x - 1)) ? 1u : 0u;
    __syncthreads();
    if (lastFlag) {
        __shared__ float tv[128];
        if (tid < 128) {
            float s = 0.0f;
#pragma unroll
            for (int g = 0; g < NSLOT; ++g)
                s += atomicAdd(&tslot[g * 128 + tid], 0.0f);  // coherent reads
            tv[tid] = s * invN;
        }
        __syncthreads();
        for (int d = tid; d < OUT; d += 256) {
            float a = b2[d];
#pragma unroll 4
            for (int kk = 0; kk < 128; ++kk) a += tv[kk] * W2[kk * OUT + d];
            out[d] = a;
        }
    }
}

extern "C" void kernel_launch(void* const* d_in, const int* in_sizes, int n_in,
                              void* d_out, int out_size, void* d_ws, size_t ws_size,
                              hipStream_t stream) {
    const float* x          = (const float*)d_in[0];
    const int*   edge_index = (const int*)  d_in[1];
    const float* W1         = (const float*)d_in[2];
    const float* b1         = (const float*)d_in[3];
    const float* W2         = (const float*)d_in[4];
    const float* b2         = (const float*)d_in[5];
    float* out = (float*)d_out;

    const int N   = in_sizes[0];      // 100000
    const int E   = in_sizes[1] / 2;  // 1600000
    const int OUT = in_sizes[5];      // 400

    const int* row = edge_index;
    const int* col = edge_index + E;

    const int NB = (N + BKT_SIZE - 1) >> BKT_BITS;   // 25
    const int stride = NB * BKT_SIZE;                // 102400

    // workspace layout
    char* p = (char*)d_ws;
    float* dinv  = (float*)p; p += (size_t)N * 4;
    float* u     = (float*)p; p += (size_t)N * 4;
    float* tslot = (float*)p; p += (size_t)NSLOT * 128 * 4;   // 16 KB
    int*   ints  = (int*)p;   p += 512;              // 128 ints: curC|curR|cnt
    int*   SC    = (int*)p;   p += (size_t)NB * CAP * 4;
    int*   SR    = (int*)p;   p += (size_t)NB * CAP * 4;
    float* P     = (float*)p;                        // max(SLICES_D, 2*SLICES)*stride
    float* Ps    = P;                                // aliases Pd (sequential phases)
    float* Pw    = P + (size_t)SLICES * stride;

    int* curC = ints;
    int* curR = ints + 32;
    unsigned* cnt = (unsigned*)(ints + 64);

    const int TILE   = 256 * EPT;
    const int nTiles = (E + TILE - 1) / TILE;        // 782 -> one tile per block

    init_misc<<<1, 128, 0, stream>>>(curC, curR, tslot, cnt);
    scatter_edges<<<nTiles, 256, 0, stream>>>(row, col, SC, SR, curC, curR, E);
    hist_deg<<<NB * SLICES_D, 256, 0, stream>>>(SC, curC, P, stride);
    finalize_deg<<<(N + 255) / 256, 256, 0, stream>>>(P, x, dinv, u, N, stride);
    const int half = NB * SLICES;
    hist_gather_both<<<2 * half, 256, 0, stream>>>(SC, SR, curC, curR, u, dinv,
                                                   Ps, Pw, stride, half);
    fused_node<<<(N + 255) / 256, 256, 0, stream>>>(Ps, Pw, dinv, x, W1, b1,
                                                    tslot, N, stride,
                                                    W2, b2, out, OUT,
                                                    1.0f / (float)N, cnt);
}